// Round 6
// baseline (75.526 us; speedup 1.0000x reference)
//
#include <hip/hip_runtime.h>

// RoIAlign dense (11x11 bilinear) + 3x3/s2 max pool -> [K=2048, C=256, 5, 5]
// features: [B=4, C=256, H=100, W=100] f32 (NCHW), rois: [K,5] f32
//
// Ladder: R1 190us (NCHW gather, TA line-bound) -> R2 45us (NHWC lane=channel)
// -> R3/R4 branchy dedup regressions -> R5 42us (static SGPR-addressed,
// VGPR 52). R5 sits at the L1-byte floor (~26us: 484 tap loads x 256B per
// wave-roi). R6 halves L1 bytes via bf16: NHWC intermediate stored as packed
// bf16 channel-PAIRS (u32). One dword load = 2 channels; 2 waves cover 256
// channels. Unpack = shift-left-16 (bf16->f32 is free). Transpose write side
// also halves (82 -> 61.5 MB HBM).
// Error budget: bf16 RTNE adds <=0.031 through convex bilinear+max;
// threshold 0.089, previous absmax 0.0156.

constexpr int Bn = 4, Cn = 256, Hn = 100, Wn = 100;
constexpr int HWn = Hn * Wn;
constexpr int PAIRS = Cn / 2;            // 128 channel pairs
constexpr float SCALE = 0.0625f;

__device__ __forceinline__ unsigned int bfpack(float a, float b) {
    // RTNE f32->bf16, pack (a -> low16, b -> high16). Inputs finite.
    unsigned int ua = __float_as_uint(a), ub = __float_as_uint(b);
    ua = (ua + 0x7FFFu + ((ua >> 16) & 1u)) >> 16;
    ub = (ub + 0x7FFFu + ((ub >> 16) & 1u)) & 0xFFFF0000u;
    return ua | ub;
}
__device__ __forceinline__ float lo16(unsigned int u) { return __uint_as_float(u << 16); }
__device__ __forceinline__ float hi16(unsigned int u) { return __uint_as_float(u & 0xFFFF0000u); }

// ------------- Kernel 1: NCHW f32 -> NHWC bf16-pair (u32) transpose -------------
__global__ __launch_bounds__(256)
void nchw_to_nhwc_bf16(const float* __restrict__ in, unsigned int* __restrict__ out)
{
    __shared__ float tile[64][65];           // [channel][spatial], +1 pad
    const int s0 = blockIdx.x * 64;
    const int c0 = blockIdx.y * 64;          // channel tile base
    const int b  = blockIdx.z;
    const int t  = threadIdx.x;

    {   // load: thread -> channel, 4 consecutive spatial (dwordx4)
        const int cl = t >> 4;
        const int s4 = (t & 15) * 4;
        const float* ip = in + ((size_t)b * Cn + c0) * HWn + s0;
#pragma unroll
        for (int pass = 0; pass < 4; ++pass) {
            const int c = pass * 16 + cl;
            if (s0 + s4 + 3 < HWn) {
                const float4 v = *(const float4*)(ip + (size_t)c * HWn + s4);
                tile[c][s4 + 0] = v.x; tile[c][s4 + 1] = v.y;
                tile[c][s4 + 2] = v.z; tile[c][s4 + 3] = v.w;
            } else {
#pragma unroll
                for (int i = 0; i < 4; ++i)
                    tile[c][s4 + i] = (s0 + s4 + i < HWn) ? ip[(size_t)c * HWn + s4 + i] : 0.0f;
            }
        }
    }
    __syncthreads();
    {   // store: thread -> spatial s, packed pairs (uint2 = 4 channels)
        const int s = t >> 2;                // 0..63
        const int q = t & 3;
        if (s0 + s < HWn) {
            unsigned int* op = out + ((size_t)b * HWn + (s0 + s)) * PAIRS + (c0 >> 1);
#pragma unroll
            for (int i = 0; i < 4; ++i) {
                const int p = q * 2 + i * 8; // even pair index 0..30
                uint2 v;
                v.x = bfpack(tile[2 * p + 0][s], tile[2 * p + 1][s]);
                v.y = bfpack(tile[2 * p + 2][s], tile[2 * p + 3][s]);
                *(uint2*)(op + p) = v;
            }
        }
    }
}

// ------------- Kernel 2: RoIAlign+pool, lane = channel pair -------------
__global__ __launch_bounds__(256)
void roipool_pair(const unsigned int* __restrict__ f, const float* __restrict__ rois,
                  float* __restrict__ out)
{
    __shared__ float stage[4][PAIRS * 2 * 5];   // per-wave, per-ph: 128ch x 5 = 10.24 KB total
    const int tid  = threadIdx.x;
    const int wid  = tid >> 6;
    const int lane = tid & 63;
    const int k    = blockIdx.x * 2 + (wid >> 1);   // 2 rois per block
    const int half = wid & 1;                        // channel half (0/1)

    const float x1 = rois[k * 5 + 1] * SCALE;
    const float y1 = rois[k * 5 + 2] * SCALE;
    const float x2 = rois[k * 5 + 3] * SCALE;
    const float y2 = rois[k * 5 + 4] * SCALE;
    const int   b  = __builtin_amdgcn_readfirstlane((int)rois[k * 5 + 0]);

    const int pi = half * 64 + lane;                 // pair index 0..127
    const unsigned int* fb = f + (size_t)b * HWn * PAIRS;

    // per-roi x-tap metadata: element offsets as SGPRs, weights per-lane
    int   xo0[11], xo1[11];
    float wx[11];
#pragma unroll
    for (int j = 0; j < 11; ++j) {
        const float xs  = x1 + (x2 - x1) * ((float)j * 0.1f);
        const float x0f = floorf(xs);
        wx[j] = xs - x0f;                            // weight from UNCLIPPED coord
        const int x0i = (int)x0f;
        xo0[j] = __builtin_amdgcn_readfirstlane(min(max(x0i,     0), Wn - 1)) * PAIRS;
        xo1[j] = __builtin_amdgcn_readfirstlane(min(max(x0i + 1, 0), Wn - 1)) * PAIRS;
    }

    // one dense sample row gy -> 5 x-window maxes for both channels
    auto dorow = [&](int gy, float (&dlo)[5], float (&dhi)[5]) {
        const float ys  = y1 + (y2 - y1) * ((float)gy * 0.1f);
        const float y0f = floorf(ys);
        const float wy  = ys - y0f;
        const int   y0i = (int)y0f;
        const int r0 = __builtin_amdgcn_readfirstlane(min(max(y0i,     0), Hn - 1));
        const int r1 = __builtin_amdgcn_readfirstlane(min(max(y0i + 1, 0), Hn - 1));
        const unsigned int* rp0 = fb + (size_t)(r0 * Wn) * PAIRS;  // uniform row ptrs
        const unsigned int* rp1 = fb + (size_t)(r1 * Wn) * PAIRS;
#pragma unroll
        for (int j = 0; j < 11; ++j) {
            const unsigned int* p00 = rp0 + xo0[j];  // uniform tap ptrs (SALU)
            const unsigned int* p01 = rp0 + xo1[j];
            const unsigned int* p10 = rp1 + xo0[j];
            const unsigned int* p11 = rp1 + xo1[j];
            const unsigned int u00 = p00[pi];
            const unsigned int u01 = p01[pi];
            const unsigned int u10 = p10[pi];
            const unsigned int u11 = p11[pi];
            // low channel
            float a00 = lo16(u00), a01 = lo16(u01), a10 = lo16(u10), a11 = lo16(u11);
            float X0 = a00 + wx[j] * (a01 - a00);
            float X1 = a10 + wx[j] * (a11 - a10);
            const float sl = X0 + wy * (X1 - X0);
            // high channel
            float b00 = hi16(u00), b01 = hi16(u01), b10 = hi16(u10), b11 = hi16(u11);
            X0 = b00 + wx[j] * (b01 - b00);
            X1 = b10 + wx[j] * (b11 - b10);
            const float sh = X0 + wy * (X1 - X0);
            // fold into 5 x-window maxes (compile-time branch pattern)
            if (j == 0)      { dlo[0] = sl; dhi[0] = sh; }
            else if (j & 1)  { dlo[j >> 1] = fmaxf(dlo[j >> 1], sl);
                               dhi[j >> 1] = fmaxf(dhi[j >> 1], sh); }
            else {
                dlo[(j >> 1) - 1] = fmaxf(dlo[(j >> 1) - 1], sl);
                dhi[(j >> 1) - 1] = fmaxf(dhi[(j >> 1) - 1], sh);
                if (j < 10) { dlo[j >> 1] = sl; dhi[j >> 1] = sh; }
            }
        }
    };

    float plo[5], phi[5];
    dorow(0, plo, phi);
    float* stw = stage[wid];
    const size_t obase = ((size_t)k * Cn + (size_t)half * 128) * 25;

#pragma unroll
    for (int ph = 0; ph < 5; ++ph) {
        float tlo[5], thi[5], nlo[5], nhi[5];
        dorow(2 * ph + 1, tlo, thi);
        dorow(2 * ph + 2, nlo, nhi);
#pragma unroll
        for (int pw = 0; pw < 5; ++pw) {
            stw[(2 * lane + 0) * 5 + pw] = fmaxf(fmaxf(plo[pw], tlo[pw]), nlo[pw]);
            stw[(2 * lane + 1) * 5 + pw] = fmaxf(fmaxf(phi[pw], thi[pw]), nhi[pw]);
            plo[pw] = nlo[pw]; phi[pw] = nhi[pw];
        }
        asm volatile("" ::: "memory");   // same-wave LDS in-order; pin compiler order
        // copy this ph-row out: 640 floats = 128 ch x 5, runs of 5 contiguous
#pragma unroll
        for (int i = 0; i < 10; ++i) {
            const int flat = i * 64 + lane;          // 0..639
            const int c    = flat / 5;               // 0..127 (const-div -> magic mul)
            const int pw   = flat - c * 5;
            out[obase + (size_t)c * 25 + ph * 5 + pw] = stw[flat];
        }
        asm volatile("" ::: "memory");
    }
}

// ------------- Fallback (reads NCHW directly) if workspace too small -------------
__global__ __launch_bounds__(256)
void roialign_pool_fallback(const float* __restrict__ feats,
                            const float* __restrict__ rois,
                            float* __restrict__ out)
{
    __shared__ float smem[4][2][128];
    const int k    = blockIdx.x;
    const int tid  = threadIdx.x;
    const int wid  = tid >> 6;
    const int lane = tid & 63;

    const float x1 = rois[k * 5 + 1] * SCALE;
    const float y1 = rois[k * 5 + 2] * SCALE;
    const float x2 = rois[k * 5 + 3] * SCALE;
    const float y2 = rois[k * 5 + 4] * SCALE;
    const int   b  = (int)rois[k * 5 + 0];

    const int  p1   = 64 + lane;
    const bool act1 = (p1 < 121);
    int   o00[2], o01[2], o10[2], o11[2];
    float w00[2], w01[2], w10[2], w11[2];
#pragma unroll
    for (int r = 0; r < 2; ++r) {
        const int p  = (r == 0) ? lane : (act1 ? p1 : 120);
        const int gy = p / 11;
        const int gx = p - gy * 11;
        const float ys = y1 + (y2 - y1) * ((float)gy / 10.0f);
        const float xs = x1 + (x2 - x1) * ((float)gx / 10.0f);
        const float y0f = floorf(ys), x0f = floorf(xs);
        const float wy = ys - y0f, wxx = xs - x0f;
        const int y0i = (int)y0f, x0i = (int)x0f;
        const int y0c = min(max(y0i, 0), Hn - 1), y1c = min(max(y0i + 1, 0), Hn - 1);
        const int x0c = min(max(x0i, 0), Wn - 1), x1c = min(max(x0i + 1, 0), Wn - 1);
        o00[r] = y0c * Wn + x0c; o01[r] = y0c * Wn + x1c;
        o10[r] = y1c * Wn + x0c; o11[r] = y1c * Wn + x1c;
        w00[r] = (1.0f - wy) * (1.0f - wxx); w01[r] = (1.0f - wy) * wxx;
        w10[r] = wy * (1.0f - wxx);          w11[r] = wy * wxx;
    }
    const bool pool  = (lane < 25);
    const int  ph    = lane / 5;
    const int  pw    = lane - ph * 5;
    const int  pbase = (2 * ph) * 11 + 2 * pw;
    const float* base = feats + ((size_t)b * Cn + (size_t)wid * 64) * HWn;
    float*       op   = out + ((size_t)k * Cn + (size_t)wid * 64) * 25 + lane;
    for (int it = 0; it < 64; ++it) {
        const float* ff  = base + (size_t)it * HWn;
        float*       buf = smem[wid][it & 1];
        const float v0 = ff[o00[0]] * w00[0] + ff[o01[0]] * w01[0]
                       + ff[o10[0]] * w10[0] + ff[o11[0]] * w11[0];
        const float v1 = ff[o00[1]] * w00[1] + ff[o01[1]] * w01[1]
                       + ff[o10[1]] * w10[1] + ff[o11[1]] * w11[1];
        buf[lane] = v0;
        if (act1) buf[p1] = v1;
        if (pool) {
            float m =          buf[pbase +  0];
            m = fmaxf(m, buf[pbase +  1]);
            m = fmaxf(m, buf[pbase +  2]);
            m = fmaxf(m, buf[pbase + 11]);
            m = fmaxf(m, buf[pbase + 12]);
            m = fmaxf(m, buf[pbase + 13]);
            m = fmaxf(m, buf[pbase + 22]);
            m = fmaxf(m, buf[pbase + 23]);
            m = fmaxf(m, buf[pbase + 24]);
            op[it * 25] = m;
        }
    }
}

extern "C" void kernel_launch(void* const* d_in, const int* in_sizes, int n_in,
                              void* d_out, int out_size, void* d_ws, size_t ws_size,
                              hipStream_t stream) {
    const float* feats = (const float*)d_in[0];
    const float* rois  = (const float*)d_in[1];
    float*       out   = (float*)d_out;
    const int K = in_sizes[1] / 5;                                  // 2048
    const size_t need = (size_t)Bn * HWn * PAIRS * sizeof(unsigned int);  // 20.48 MB

    if (ws_size >= need) {
        unsigned int* nhwc = (unsigned int*)d_ws;
        dim3 tgrid((HWn + 63) / 64, Cn / 64, Bn);                   // 157 x 4 x 4
        nchw_to_nhwc_bf16<<<tgrid, 256, 0, stream>>>(feats, nhwc);
        roipool_pair<<<K / 2, 256, 0, stream>>>(nhwc, rois, out);
    } else {
        roialign_pool_fallback<<<K, 256, 0, stream>>>(feats, rois, out);
    }
}

// Round 7
// 51.438 us; speedup vs baseline: 1.4683x; 1.4683x over previous
//
#include <hip/hip_runtime.h>

// RoIAlign dense (11x11 bilinear) + 3x3/s2 max pool -> [K=2048, C=256, 5, 5]
// features: [B=4, C=256, H=100, W=100] f32 (NCHW), rois: [K,5] f32
//
// Ladder: R1 190us (NCHW gather) -> R2 45us (NHWC lane=channel) -> R3/R4
// branchy-dedup regressions -> R5 42us main (static SGPR-addressed, f32) ->
// R6 66us main (bf16 pairs halved FETCH 82.7->64.6MB, BUT per-ph scattered
// stores blew WRITE_SIZE 51->125MB via partial-line RMW and broke pipelining).
// R7 = R6 loads + R5 stores: one wave per roi-half, pooled results staged in
// per-wave LDS laid out exactly like the output, single coalesced float2 copy
// at the end (each 64B line written once, by one instruction).

constexpr int Bn = 4, Cn = 256, Hn = 100, Wn = 100;
constexpr int HWn = Hn * Wn;
constexpr int PAIRS = Cn / 2;            // 128 channel pairs
constexpr float SCALE = 0.0625f;

__device__ __forceinline__ unsigned int bfpack(float a, float b) {
    // RTNE f32->bf16, pack (a -> low16, b -> high16). Inputs finite.
    unsigned int ua = __float_as_uint(a), ub = __float_as_uint(b);
    ua = (ua + 0x7FFFu + ((ua >> 16) & 1u)) >> 16;
    ub = (ub + 0x7FFFu + ((ub >> 16) & 1u)) & 0xFFFF0000u;
    return ua | ub;
}
__device__ __forceinline__ float lo16(unsigned int u) { return __uint_as_float(u << 16); }
__device__ __forceinline__ float hi16(unsigned int u) { return __uint_as_float(u & 0xFFFF0000u); }

// ------------- Kernel 1: NCHW f32 -> NHWC bf16-pair (u32) transpose -------------
__global__ __launch_bounds__(256)
void nchw_to_nhwc_bf16(const float* __restrict__ in, unsigned int* __restrict__ out)
{
    __shared__ float tile[64][65];           // [channel][spatial], +1 pad
    const int s0 = blockIdx.x * 64;
    const int c0 = blockIdx.y * 64;          // channel tile base
    const int b  = blockIdx.z;
    const int t  = threadIdx.x;

    {   // load: thread -> channel, 4 consecutive spatial (dwordx4)
        const int cl = t >> 4;
        const int s4 = (t & 15) * 4;
        const float* ip = in + ((size_t)b * Cn + c0) * HWn + s0;
#pragma unroll
        for (int pass = 0; pass < 4; ++pass) {
            const int c = pass * 16 + cl;
            if (s0 + s4 + 3 < HWn) {
                const float4 v = *(const float4*)(ip + (size_t)c * HWn + s4);
                tile[c][s4 + 0] = v.x; tile[c][s4 + 1] = v.y;
                tile[c][s4 + 2] = v.z; tile[c][s4 + 3] = v.w;
            } else {
#pragma unroll
                for (int i = 0; i < 4; ++i)
                    tile[c][s4 + i] = (s0 + s4 + i < HWn) ? ip[(size_t)c * HWn + s4 + i] : 0.0f;
            }
        }
    }
    __syncthreads();
    {   // store: thread -> spatial s, packed pairs (uint2 = 4 channels)
        const int s = t >> 2;                // 0..63
        const int q = t & 3;
        if (s0 + s < HWn) {
            unsigned int* op = out + ((size_t)b * HWn + (s0 + s)) * PAIRS + (c0 >> 1);
#pragma unroll
            for (int i = 0; i < 4; ++i) {
                const int p = q * 2 + i * 8; // even pair index 0..30
                uint2 v;
                v.x = bfpack(tile[2 * p + 0][s], tile[2 * p + 1][s]);
                v.y = bfpack(tile[2 * p + 2][s], tile[2 * p + 3][s]);
                *(uint2*)(op + p) = v;
            }
        }
    }
}

// ------------- Kernel 2: RoIAlign+pool, lane = channel pair -------------
// 128-thread block = 1 roi; wave wid = channel half (64 pairs each).
__global__ __launch_bounds__(128)
void roipool_pair(const unsigned int* __restrict__ f, const float* __restrict__ rois,
                  float* __restrict__ out)
{
    __shared__ float stage[2][PAIRS * 2 * 5 * 5 / 2];  // [wave][3200] = 25.6 KB
    const int tid  = threadIdx.x;
    const int wid  = tid >> 6;                // channel half (0/1)
    const int lane = tid & 63;
    const int k    = blockIdx.x;

    const float x1 = rois[k * 5 + 1] * SCALE;
    const float y1 = rois[k * 5 + 2] * SCALE;
    const float x2 = rois[k * 5 + 3] * SCALE;
    const float y2 = rois[k * 5 + 4] * SCALE;
    const int   b  = __builtin_amdgcn_readfirstlane((int)rois[k * 5 + 0]);

    const int pi = wid * 64 + lane;           // pair index 0..127
    const unsigned int* fb = f + (size_t)b * HWn * PAIRS;

    // per-roi x-tap metadata: element offsets as SGPRs, weights per-lane
    int   xo0[11], xo1[11];
    float wx[11];
#pragma unroll
    for (int j = 0; j < 11; ++j) {
        const float xs  = x1 + (x2 - x1) * ((float)j * 0.1f);
        const float x0f = floorf(xs);
        wx[j] = xs - x0f;                     // weight from UNCLIPPED coord
        const int x0i = (int)x0f;
        xo0[j] = __builtin_amdgcn_readfirstlane(min(max(x0i,     0), Wn - 1)) * PAIRS;
        xo1[j] = __builtin_amdgcn_readfirstlane(min(max(x0i + 1, 0), Wn - 1)) * PAIRS;
    }

    // one dense sample row gy -> 5 x-window maxes for both channels of the pair
    auto dorow = [&](int gy, float (&dlo)[5], float (&dhi)[5]) {
        const float ys  = y1 + (y2 - y1) * ((float)gy * 0.1f);
        const float y0f = floorf(ys);
        const float wy  = ys - y0f;
        const int   y0i = (int)y0f;
        const int r0 = __builtin_amdgcn_readfirstlane(min(max(y0i,     0), Hn - 1));
        const int r1 = __builtin_amdgcn_readfirstlane(min(max(y0i + 1, 0), Hn - 1));
        const unsigned int* rp0 = fb + (size_t)(r0 * Wn) * PAIRS;
        const unsigned int* rp1 = fb + (size_t)(r1 * Wn) * PAIRS;
#pragma unroll
        for (int j = 0; j < 11; ++j) {
            const unsigned int u00 = (rp0 + xo0[j])[pi];   // uniform ptr + lane idx
            const unsigned int u01 = (rp0 + xo1[j])[pi];
            const unsigned int u10 = (rp1 + xo0[j])[pi];
            const unsigned int u11 = (rp1 + xo1[j])[pi];
            float a00 = lo16(u00), a01 = lo16(u01), a10 = lo16(u10), a11 = lo16(u11);
            float X0 = a00 + wx[j] * (a01 - a00);
            float X1 = a10 + wx[j] * (a11 - a10);
            const float sl = X0 + wy * (X1 - X0);
            float b00 = hi16(u00), b01 = hi16(u01), b10 = hi16(u10), b11 = hi16(u11);
            X0 = b00 + wx[j] * (b01 - b00);
            X1 = b10 + wx[j] * (b11 - b10);
            const float sh = X0 + wy * (X1 - X0);
            if (j == 0)      { dlo[0] = sl; dhi[0] = sh; }
            else if (j & 1)  { dlo[j >> 1] = fmaxf(dlo[j >> 1], sl);
                               dhi[j >> 1] = fmaxf(dhi[j >> 1], sh); }
            else {
                dlo[(j >> 1) - 1] = fmaxf(dlo[(j >> 1) - 1], sl);
                dhi[(j >> 1) - 1] = fmaxf(dhi[(j >> 1) - 1], sh);
                if (j < 10) { dlo[j >> 1] = sl; dhi[j >> 1] = sh; }
            }
        }
    };

    float plo[5], phi[5];
    dorow(0, plo, phi);
    float* stw = stage[wid];
    float* st0 = &stw[(2 * lane + 0) * 25];   // lane's low-channel 25-block
    float* st1 = &stw[(2 * lane + 1) * 25];   // lane's high-channel 25-block

#pragma unroll
    for (int ph = 0; ph < 5; ++ph) {
        float tlo[5], thi[5], nlo[5], nhi[5];
        dorow(2 * ph + 1, tlo, thi);
        dorow(2 * ph + 2, nlo, nhi);
#pragma unroll
        for (int pw = 0; pw < 5; ++pw) {
            st0[ph * 5 + pw] = fmaxf(fmaxf(plo[pw], tlo[pw]), nlo[pw]);
            st1[ph * 5 + pw] = fmaxf(fmaxf(phi[pw], thi[pw]), nhi[pw]);
            plo[pw] = nlo[pw]; phi[pw] = nhi[pw];
        }
    }

    // same-wave LDS in-order; pin compiler ordering before the copy-out
    asm volatile("" ::: "memory");

    // single coalesced copy: 3200 floats = 25 iters x 64 lanes x float2;
    // stage layout == output layout for this (roi, half) -> every 64B line
    // written exactly once.
    float* ob = out + (size_t)k * (Cn * 25) + (size_t)wid * 3200;
#pragma unroll
    for (int i = 0; i < 25; ++i) {
        const int idx = (i * 64 + lane) * 2;
        *(float2*)(ob + idx) = *(const float2*)(stw + idx);
    }
}

// ------------- Fallback (reads NCHW directly) if workspace too small -------------
__global__ __launch_bounds__(256)
void roialign_pool_fallback(const float* __restrict__ feats,
                            const float* __restrict__ rois,
                            float* __restrict__ out)
{
    __shared__ float smem[4][2][128];
    const int k    = blockIdx.x;
    const int tid  = threadIdx.x;
    const int wid  = tid >> 6;
    const int lane = tid & 63;

    const float x1 = rois[k * 5 + 1] * SCALE;
    const float y1 = rois[k * 5 + 2] * SCALE;
    const float x2 = rois[k * 5 + 3] * SCALE;
    const float y2 = rois[k * 5 + 4] * SCALE;
    const int   b  = (int)rois[k * 5 + 0];

    const int  p1   = 64 + lane;
    const bool act1 = (p1 < 121);
    int   o00[2], o01[2], o10[2], o11[2];
    float w00[2], w01[2], w10[2], w11[2];
#pragma unroll
    for (int r = 0; r < 2; ++r) {
        const int p  = (r == 0) ? lane : (act1 ? p1 : 120);
        const int gy = p / 11;
        const int gx = p - gy * 11;
        const float ys = y1 + (y2 - y1) * ((float)gy / 10.0f);
        const float xs = x1 + (x2 - x1) * ((float)gx / 10.0f);
        const float y0f = floorf(ys), x0f = floorf(xs);
        const float wy = ys - y0f, wxx = xs - x0f;
        const int y0i = (int)y0f, x0i = (int)x0f;
        const int y0c = min(max(y0i, 0), Hn - 1), y1c = min(max(y0i + 1, 0), Hn - 1);
        const int x0c = min(max(x0i, 0), Wn - 1), x1c = min(max(x0i + 1, 0), Wn - 1);
        o00[r] = y0c * Wn + x0c; o01[r] = y0c * Wn + x1c;
        o10[r] = y1c * Wn + x0c; o11[r] = y1c * Wn + x1c;
        w00[r] = (1.0f - wy) * (1.0f - wxx); w01[r] = (1.0f - wy) * wxx;
        w10[r] = wy * (1.0f - wxx);          w11[r] = wy * wxx;
    }
    const bool pool  = (lane < 25);
    const int  ph    = lane / 5;
    const int  pw    = lane - ph * 5;
    const int  pbase = (2 * ph) * 11 + 2 * pw;
    const float* base = feats + ((size_t)b * Cn + (size_t)wid * 64) * HWn;
    float*       op   = out + ((size_t)k * Cn + (size_t)wid * 64) * 25 + lane;
    for (int it = 0; it < 64; ++it) {
        const float* ff  = base + (size_t)it * HWn;
        float*       buf = smem[wid][it & 1];
        const float v0 = ff[o00[0]] * w00[0] + ff[o01[0]] * w01[0]
                       + ff[o10[0]] * w10[0] + ff[o11[0]] * w11[0];
        const float v1 = ff[o00[1]] * w00[1] + ff[o01[1]] * w01[1]
                       + ff[o10[1]] * w10[1] + ff[o11[1]] * w11[1];
        buf[lane] = v0;
        if (act1) buf[p1] = v1;
        if (pool) {
            float m =          buf[pbase +  0];
            m = fmaxf(m, buf[pbase +  1]);
            m = fmaxf(m, buf[pbase +  2]);
            m = fmaxf(m, buf[pbase + 11]);
            m = fmaxf(m, buf[pbase + 12]);
            m = fmaxf(m, buf[pbase + 13]);
            m = fmaxf(m, buf[pbase + 22]);
            m = fmaxf(m, buf[pbase + 23]);
            m = fmaxf(m, buf[pbase + 24]);
            op[it * 25] = m;
        }
    }
}

extern "C" void kernel_launch(void* const* d_in, const int* in_sizes, int n_in,
                              void* d_out, int out_size, void* d_ws, size_t ws_size,
                              hipStream_t stream) {
    const float* feats = (const float*)d_in[0];
    const float* rois  = (const float*)d_in[1];
    float*       out   = (float*)d_out;
    const int K = in_sizes[1] / 5;                                  // 2048
    const size_t need = (size_t)Bn * HWn * PAIRS * sizeof(unsigned int);  // 20.48 MB

    if (ws_size >= need) {
        unsigned int* nhwc = (unsigned int*)d_ws;
        dim3 tgrid((HWn + 63) / 64, Cn / 64, Bn);                   // 157 x 4 x 4
        nchw_to_nhwc_bf16<<<tgrid, 256, 0, stream>>>(feats, nhwc);
        roipool_pair<<<K, 128, 0, stream>>>(nhwc, rois, out);
    } else {
        roialign_pool_fallback<<<K, 256, 0, stream>>>(feats, rois, out);
    }
}

// Round 8
// 45.567 us; speedup vs baseline: 1.6575x; 1.1288x over previous
//
#include <hip/hip_runtime.h>

// RoIAlign dense (11x11 bilinear) + 3x3/s2 max pool -> [K=2048, C=256, 5, 5]
// features: [B=4, C=256, H=100, W=100] f32 (NCHW), rois: [K,5] f32
//
// Ladder: R1 190us -> R2 45 (NHWC lane=channel) -> R5 42 main (static SGPR
// addressing, f32) -> R6 66 main (bf16 pairs cut FETCH but scattered stores
// blew WRITE 51->125MB) -> R7 ~41 main (store fix, BUT 128-thr block with
// 25.6KB stage -> 6 blocks/CU -> only 12 waves/CU; occupancy ate bf16 gain).
// R8: re-pair channels as (c, c+128) in the transpose so each wave's lo/hi
// channel outputs are CONTIGUOUS 1600-float blocks -> stage = 1600 floats
// (12.8 KB/block) -> 12 blocks/CU = 24 waves/CU. lo staged in-loop, hi held
// in 25 regs and staged after; two coalesced copy phases, every 64B output
// line written exactly once.

constexpr int Bn = 4, Cn = 256, Hn = 100, Wn = 100;
constexpr int HWn = Hn * Wn;
constexpr int PAIRS = Cn / 2;            // 128 channel pairs
constexpr float SCALE = 0.0625f;

__device__ __forceinline__ unsigned int bfpack(float a, float b) {
    // RTNE f32->bf16, pack (a -> low16, b -> high16). Inputs finite.
    unsigned int ua = __float_as_uint(a), ub = __float_as_uint(b);
    ua = (ua + 0x7FFFu + ((ua >> 16) & 1u)) >> 16;
    ub = (ub + 0x7FFFu + ((ub >> 16) & 1u)) & 0xFFFF0000u;
    return ua | ub;
}
__device__ __forceinline__ float lo16(unsigned int u) { return __uint_as_float(u << 16); }
__device__ __forceinline__ float hi16(unsigned int u) { return __uint_as_float(u & 0xFFFF0000u); }

// ------- Kernel 1: NCHW f32 -> NHWC bf16 (c, c+128)-pair (u32) transpose -------
// blockIdx.y covers 32 pairs: pairs p0..p0+31 = channels {p0+r, p0+r+128}.
__global__ __launch_bounds__(256)
void nchw_to_nhwc_bf16(const float* __restrict__ in, unsigned int* __restrict__ out)
{
    __shared__ float tile[64][65];           // rows 0..31: ch p0+r; 32..63: ch p0+96+r
    const int s0 = blockIdx.x * 64;
    const int p0 = blockIdx.y * 32;          // pair-tile base (0,32,64,96)
    const int b  = blockIdx.z;
    const int t  = threadIdx.x;

    {   // load: thread -> tile row, 4 consecutive spatial (dwordx4)
        const int cl = t >> 4;               // 0..15
        const int s4 = (t & 15) * 4;         // 0..60
        const float* ip = in + (size_t)b * Cn * HWn + s0;
#pragma unroll
        for (int pass = 0; pass < 4; ++pass) {
            const int r  = pass * 16 + cl;   // tile row 0..63
            const int ch = (pass < 2) ? (p0 + r) : (p0 + 96 + r);  // +128 for hi half
            if (s0 + s4 + 3 < HWn) {
                const float4 v = *(const float4*)(ip + (size_t)ch * HWn + s4);
                tile[r][s4 + 0] = v.x; tile[r][s4 + 1] = v.y;
                tile[r][s4 + 2] = v.z; tile[r][s4 + 3] = v.w;
            } else {
#pragma unroll
                for (int i = 0; i < 4; ++i)
                    tile[r][s4 + i] = (s0 + s4 + i < HWn) ? ip[(size_t)ch * HWn + s4 + i] : 0.0f;
            }
        }
    }
    __syncthreads();
    {   // store: thread -> spatial s, uint2 = pairs (p0+li, p0+li+1)
        const int s = t >> 2;                // 0..63
        const int q = t & 3;
        if (s0 + s < HWn) {
            unsigned int* op = out + ((size_t)b * HWn + (s0 + s)) * PAIRS + p0;
#pragma unroll
            for (int i = 0; i < 4; ++i) {
                const int li = q * 2 + i * 8;            // even, 0..30
                uint2 v;
                v.x = bfpack(tile[li    ][s], tile[li + 32][s]);  // pair p0+li
                v.y = bfpack(tile[li + 1][s], tile[li + 33][s]);  // pair p0+li+1
                *(uint2*)(op + li) = v;
            }
        }
    }
}

// ------------- Kernel 2: RoIAlign+pool, lane = channel pair -------------
// 128-thread block = 1 roi; wave wid covers pairs wid*64..+63
// (= channels wid*64..+63 lo, +128 hi). Stage 1600 floats/wave = 12.8 KB.
__global__ __launch_bounds__(128)
void roipool_pair(const unsigned int* __restrict__ f, const float* __restrict__ rois,
                  float* __restrict__ out)
{
    __shared__ float stage[2][1600];          // [wave][64ch x 25], 12.8 KB
    const int tid  = threadIdx.x;
    const int wid  = tid >> 6;
    const int lane = tid & 63;
    const int k    = blockIdx.x;

    const float x1 = rois[k * 5 + 1] * SCALE;
    const float y1 = rois[k * 5 + 2] * SCALE;
    const float x2 = rois[k * 5 + 3] * SCALE;
    const float y2 = rois[k * 5 + 4] * SCALE;
    const int   b  = __builtin_amdgcn_readfirstlane((int)rois[k * 5 + 0]);

    const int pi = wid * 64 + lane;           // pair index 0..127
    const unsigned int* fb = f + (size_t)b * HWn * PAIRS;

    // per-roi x-tap metadata: element offsets as SGPRs, weights per-lane
    int   xo0[11], xo1[11];
    float wx[11];
#pragma unroll
    for (int j = 0; j < 11; ++j) {
        const float xs  = x1 + (x2 - x1) * ((float)j * 0.1f);
        const float x0f = floorf(xs);
        wx[j] = xs - x0f;                     // weight from UNCLIPPED coord
        const int x0i = (int)x0f;
        xo0[j] = __builtin_amdgcn_readfirstlane(min(max(x0i,     0), Wn - 1)) * PAIRS;
        xo1[j] = __builtin_amdgcn_readfirstlane(min(max(x0i + 1, 0), Wn - 1)) * PAIRS;
    }

    // one dense sample row gy -> 5 x-window maxes for both channels of the pair
    auto dorow = [&](int gy, float (&dlo)[5], float (&dhi)[5]) {
        const float ys  = y1 + (y2 - y1) * ((float)gy * 0.1f);
        const float y0f = floorf(ys);
        const float wy  = ys - y0f;
        const int   y0i = (int)y0f;
        const int r0 = __builtin_amdgcn_readfirstlane(min(max(y0i,     0), Hn - 1));
        const int r1 = __builtin_amdgcn_readfirstlane(min(max(y0i + 1, 0), Hn - 1));
        const unsigned int* rp0 = fb + (size_t)(r0 * Wn) * PAIRS;
        const unsigned int* rp1 = fb + (size_t)(r1 * Wn) * PAIRS;
#pragma unroll
        for (int j = 0; j < 11; ++j) {
            const unsigned int u00 = (rp0 + xo0[j])[pi];   // uniform ptr + lane idx
            const unsigned int u01 = (rp0 + xo1[j])[pi];
            const unsigned int u10 = (rp1 + xo0[j])[pi];
            const unsigned int u11 = (rp1 + xo1[j])[pi];
            float a00 = lo16(u00), a01 = lo16(u01), a10 = lo16(u10), a11 = lo16(u11);
            float X0 = a00 + wx[j] * (a01 - a00);
            float X1 = a10 + wx[j] * (a11 - a10);
            const float sl = X0 + wy * (X1 - X0);
            float b00 = hi16(u00), b01 = hi16(u01), b10 = hi16(u10), b11 = hi16(u11);
            X0 = b00 + wx[j] * (b01 - b00);
            X1 = b10 + wx[j] * (b11 - b10);
            const float sh = X0 + wy * (X1 - X0);
            if (j == 0)      { dlo[0] = sl; dhi[0] = sh; }
            else if (j & 1)  { dlo[j >> 1] = fmaxf(dlo[j >> 1], sl);
                               dhi[j >> 1] = fmaxf(dhi[j >> 1], sh); }
            else {
                dlo[(j >> 1) - 1] = fmaxf(dlo[(j >> 1) - 1], sl);
                dhi[(j >> 1) - 1] = fmaxf(dhi[(j >> 1) - 1], sh);
                if (j < 10) { dlo[j >> 1] = sl; dhi[j >> 1] = sh; }
            }
        }
    };

    float plo[5], phi[5], ohi[25];
    dorow(0, plo, phi);
    float* stw = stage[wid];
    float* stl = &stw[lane * 25];             // lane's lo-channel 25-block

#pragma unroll
    for (int ph = 0; ph < 5; ++ph) {
        float tlo[5], thi[5], nlo[5], nhi[5];
        dorow(2 * ph + 1, tlo, thi);
        dorow(2 * ph + 2, nlo, nhi);
#pragma unroll
        for (int pw = 0; pw < 5; ++pw) {
            stl[ph * 5 + pw]  = fmaxf(fmaxf(plo[pw], tlo[pw]), nlo[pw]);  // lo -> LDS
            ohi[ph * 5 + pw]  = fmaxf(fmaxf(phi[pw], thi[pw]), nhi[pw]);  // hi -> regs
            plo[pw] = nlo[pw]; phi[pw] = nhi[pw];
        }
    }

    // phase A: copy lo block (channels wid*64..+63 = contiguous 1600 floats)
    asm volatile("" ::: "memory");
    float* obl = out + (size_t)k * (Cn * 25) + (size_t)wid * 1600;
#pragma unroll
    for (int i = 0; i < 25; ++i)
        obl[i * 64 + lane] = stw[i * 64 + lane];

    // phase B: stage hi from regs, copy hi block (channels +128 -> +3200 floats)
    asm volatile("" ::: "memory");
#pragma unroll
    for (int p = 0; p < 25; ++p)
        stl[p] = ohi[p];
    asm volatile("" ::: "memory");
    float* obh = obl + 3200;
#pragma unroll
    for (int i = 0; i < 25; ++i)
        obh[i * 64 + lane] = stw[i * 64 + lane];
}

// ------------- Fallback (reads NCHW directly) if workspace too small -------------
__global__ __launch_bounds__(256)
void roialign_pool_fallback(const float* __restrict__ feats,
                            const float* __restrict__ rois,
                            float* __restrict__ out)
{
    __shared__ float smem[4][2][128];
    const int k    = blockIdx.x;
    const int tid  = threadIdx.x;
    const int wid  = tid >> 6;
    const int lane = tid & 63;

    const float x1 = rois[k * 5 + 1] * SCALE;
    const float y1 = rois[k * 5 + 2] * SCALE;
    const float x2 = rois[k * 5 + 3] * SCALE;
    const float y2 = rois[k * 5 + 4] * SCALE;
    const int   b  = (int)rois[k * 5 + 0];

    const int  p1   = 64 + lane;
    const bool act1 = (p1 < 121);
    int   o00[2], o01[2], o10[2], o11[2];
    float w00[2], w01[2], w10[2], w11[2];
#pragma unroll
    for (int r = 0; r < 2; ++r) {
        const int p  = (r == 0) ? lane : (act1 ? p1 : 120);
        const int gy = p / 11;
        const int gx = p - gy * 11;
        const float ys = y1 + (y2 - y1) * ((float)gy / 10.0f);
        const float xs = x1 + (x2 - x1) * ((float)gx / 10.0f);
        const float y0f = floorf(ys), x0f = floorf(xs);
        const float wy = ys - y0f, wxx = xs - x0f;
        const int y0i = (int)y0f, x0i = (int)x0f;
        const int y0c = min(max(y0i, 0), Hn - 1), y1c = min(max(y0i + 1, 0), Hn - 1);
        const int x0c = min(max(x0i, 0), Wn - 1), x1c = min(max(x0i + 1, 0), Wn - 1);
        o00[r] = y0c * Wn + x0c; o01[r] = y0c * Wn + x1c;
        o10[r] = y1c * Wn + x0c; o11[r] = y1c * Wn + x1c;
        w00[r] = (1.0f - wy) * (1.0f - wxx); w01[r] = (1.0f - wy) * wxx;
        w10[r] = wy * (1.0f - wxx);          w11[r] = wy * wxx;
    }
    const bool pool  = (lane < 25);
    const int  ph    = lane / 5;
    const int  pw    = lane - ph * 5;
    const int  pbase = (2 * ph) * 11 + 2 * pw;
    const float* base = feats + ((size_t)b * Cn + (size_t)wid * 64) * HWn;
    float*       op   = out + ((size_t)k * Cn + (size_t)wid * 64) * 25 + lane;
    for (int it = 0; it < 64; ++it) {
        const float* ff  = base + (size_t)it * HWn;
        float*       buf = smem[wid][it & 1];
        const float v0 = ff[o00[0]] * w00[0] + ff[o01[0]] * w01[0]
                       + ff[o10[0]] * w10[0] + ff[o11[0]] * w11[0];
        const float v1 = ff[o00[1]] * w00[1] + ff[o01[1]] * w01[1]
                       + ff[o10[1]] * w10[1] + ff[o11[1]] * w11[1];
        buf[lane] = v0;
        if (act1) buf[p1] = v1;
        if (pool) {
            float m =          buf[pbase +  0];
            m = fmaxf(m, buf[pbase +  1]);
            m = fmaxf(m, buf[pbase +  2]);
            m = fmaxf(m, buf[pbase + 11]);
            m = fmaxf(m, buf[pbase + 12]);
            m = fmaxf(m, buf[pbase + 13]);
            m = fmaxf(m, buf[pbase + 22]);
            m = fmaxf(m, buf[pbase + 23]);
            m = fmaxf(m, buf[pbase + 24]);
            op[it * 25] = m;
        }
    }
}

extern "C" void kernel_launch(void* const* d_in, const int* in_sizes, int n_in,
                              void* d_out, int out_size, void* d_ws, size_t ws_size,
                              hipStream_t stream) {
    const float* feats = (const float*)d_in[0];
    const float* rois  = (const float*)d_in[1];
    float*       out   = (float*)d_out;
    const int K = in_sizes[1] / 5;                                  // 2048
    const size_t need = (size_t)Bn * HWn * PAIRS * sizeof(unsigned int);  // 20.48 MB

    if (ws_size >= need) {
        unsigned int* nhwc = (unsigned int*)d_ws;
        dim3 tgrid((HWn + 63) / 64, PAIRS / 32, Bn);                // 157 x 4 x 4
        nchw_to_nhwc_bf16<<<tgrid, 256, 0, stream>>>(feats, nhwc);
        roipool_pair<<<K, 128, 0, stream>>>(nhwc, rois, out);
    } else {
        roialign_pool_fallback<<<K, 256, 0, stream>>>(feats, rois, out);
    }
}